// Round 1
// baseline (753.332 us; speedup 1.0000x reference)
//
#include <hip/hip_runtime.h>
#include <hip/hip_bf16.h>

// Static problem config (BEVFormer-base-ish, 50x50 BEV grid)
#define L_TOT   19560
#define NQ      2500
#define NCAMS   6
#define EMBED   256

__device__ __forceinline__ unsigned short f2bf(float x) {
  __hip_bfloat16 h = __float2bfloat16(x);
  return *reinterpret_cast<unsigned short*>(&h);
}

// ---------------------------------------------------------------------------
// bev_mask dtype canonicalizer: harness may hand us bool as u8, i32, or f32.
// Sniff the first 3750 32-bit words (always in-bounds for all 3 layouts) and
// rewrite to a clean u8[15000] in workspace.
// ---------------------------------------------------------------------------
__global__ void canon_mask_kernel(const void* __restrict__ in,
                                  unsigned char* __restrict__ outm) {
  __shared__ int notI, notF;
  if (threadIdx.x == 0) { notI = 0; notF = 0; }
  __syncthreads();
  const unsigned int* w = (const unsigned int*)in;
  for (int i = threadIdx.x; i < 3750; i += 256) {
    unsigned int x = w[i];
    if (x != 0u && x != 1u)          atomicOr(&notI, 1);
    if (x != 0u && x != 0x3f800000u) atomicOr(&notF, 1);
  }
  __syncthreads();
  int mode = (notI == 0) ? 1 : ((notF == 0) ? 2 : 0); // 1=i32, 2=f32, 0=u8
  for (int i = threadIdx.x; i < NCAMS * NQ; i += 256) {
    unsigned char v;
    if (mode == 1)      v = (unsigned char)(w[i] != 0u);
    else if (mode == 2) v = (unsigned char)(((const float*)in)[i] != 0.0f);
    else                v = (unsigned char)(((const unsigned char*)in)[i] != 0);
    outm[i] = v;
  }
}

// ---------------------------------------------------------------------------
// q = query + query_pos
// ---------------------------------------------------------------------------
__global__ void add_qpos_kernel(const float* __restrict__ a,
                                const float* __restrict__ b,
                                float* __restrict__ o, int n) {
  int i = blockIdx.x * 256 + threadIdx.x;
  if (i < n) o[i] = a[i] + b[i];
}

// ---------------------------------------------------------------------------
// Generic f32 GEMM: C[M,N] = A[M,256] * B[N,256]^T + bias[N] (+ R[M,N])
// 64x64 tile, 256 threads, 4x4 microtile. Optional bf16 output.
// ---------------------------------------------------------------------------
template <bool BF16_OUT>
__global__ __launch_bounds__(256) void gemm_f32_kernel(
    const float* __restrict__ A, const float* __restrict__ B,
    const float* __restrict__ bias, const float* __restrict__ R,
    void* __restrict__ Cv, int M, int N) {
  __shared__ float As[16][68];
  __shared__ float Bs[16][68];
  const int tid = threadIdx.x;
  const int m0 = blockIdx.x * 64, n0 = blockIdx.y * 64;
  const int lr = tid >> 2;        // 0..63 : row within tile for loads
  const int lk = (tid & 3) * 4;   // 0,4,8,12 : k-offset for float4 load
  const int tm = tid >> 4;        // 0..15
  const int tn = tid & 15;        // 0..15

  const bool arow_ok = (m0 + lr) < M;
  const float* Ap = A + (size_t)(m0 + lr) * 256 + lk;
  const float* Bp = B + (size_t)(n0 + lr) * 256 + lk;

  float acc[4][4] = {};

  for (int kt = 0; kt < 16; ++kt) {
    float4 av = arow_ok ? *(const float4*)(Ap + kt * 16)
                        : make_float4(0.f, 0.f, 0.f, 0.f);
    float4 bv = *(const float4*)(Bp + kt * 16);
    __syncthreads();
    As[lk + 0][lr] = av.x; As[lk + 1][lr] = av.y;
    As[lk + 2][lr] = av.z; As[lk + 3][lr] = av.w;
    Bs[lk + 0][lr] = bv.x; Bs[lk + 1][lr] = bv.y;
    Bs[lk + 2][lr] = bv.z; Bs[lk + 3][lr] = bv.w;
    __syncthreads();
#pragma unroll
    for (int k = 0; k < 16; ++k) {
      const float4 a4 = *(const float4*)&As[k][tm * 4];
      const float4 b4 = *(const float4*)&Bs[k][tn * 4];
      const float aa[4] = {a4.x, a4.y, a4.z, a4.w};
      const float bb[4] = {b4.x, b4.y, b4.z, b4.w};
#pragma unroll
      for (int i = 0; i < 4; ++i)
#pragma unroll
        for (int j = 0; j < 4; ++j) acc[i][j] += aa[i] * bb[j];
    }
  }

  const int nb = n0 + tn * 4;
  float bsv[4] = {bias[nb], bias[nb + 1], bias[nb + 2], bias[nb + 3]};
#pragma unroll
  for (int i = 0; i < 4; ++i) {
    int m = m0 + tm * 4 + i;
    if (m >= M) continue;
    float o0 = acc[i][0] + bsv[0];
    float o1 = acc[i][1] + bsv[1];
    float o2 = acc[i][2] + bsv[2];
    float o3 = acc[i][3] + bsv[3];
    if (R != nullptr) {
      const float4 r4 = *(const float4*)&R[(size_t)m * N + nb];
      o0 += r4.x; o1 += r4.y; o2 += r4.z; o3 += r4.w;
    }
    if (BF16_OUT) {
      ushort4 u;
      u.x = f2bf(o0); u.y = f2bf(o1); u.z = f2bf(o2); u.w = f2bf(o3);
      *(ushort4*)((unsigned short*)Cv + (size_t)m * N + nb) = u;
    } else {
      float4 o; o.x = o0; o.y = o1; o.z = o2; o.w = o3;
      *(float4*)((float*)Cv + (size_t)m * N + nb) = o;
    }
  }
}

// ---------------------------------------------------------------------------
// Deformable sampler. One block per query (256 threads = channels).
// Thread t <-> combo (h = t>>5, l = (t>>3)&3, p = t&7) for loc/weight precompute,
// then thread t = channel (h = t>>5, d = t&31) in the gather loop.
// v is bf16, (cam, L_TOT, 256).
// ---------------------------------------------------------------------------
__global__ __launch_bounds__(256) void sampler_kernel(
    const __hip_bfloat16* __restrict__ v, const float* __restrict__ off,
    const float* __restrict__ logits, const float* __restrict__ ref,
    const unsigned char* __restrict__ mask, float* __restrict__ slots) {
  const int q = blockIdx.x;
  const int t = threadIdx.x;
  __shared__ float sx[256], sy[256], sw[256];

  // --- precompute sample locations + softmaxed attention weights ---
  {
    const int l = (t >> 3) & 3;
    const int p = t & 7;
    const int z = p & 3;  // off reshape (...,NP//NZ,NZ,2): z = p % NZ
    const float Wl[4] = {160.f, 80.f, 40.f, 20.f};
    const float Hl[4] = {92.f, 46.f, 23.f, 12.f};
    const float2 rz = ((const float2*)ref)[q * 4 + z];
    const float2 o2 = ((const float2*)off)[(size_t)q * 256 + t];
    // x = (ref_x + off_x/W)*W - 0.5 == ref_x*W + off_x - 0.5
    sx[t] = rz.x * Wl[l] + o2.x - 0.5f;
    sy[t] = rz.y * Hl[l] + o2.y - 0.5f;
    float lg = logits[q * 256 + t];
    float mx = lg;
    for (int s = 16; s; s >>= 1) mx = fmaxf(mx, __shfl_xor(mx, s, 32));
    float e = __expf(lg - mx);
    float sm = e;
    for (int s = 16; s; s >>= 1) sm += __shfl_xor(sm, s, 32);
    sw[t] = e / sm;
  }
  __syncthreads();

  const int WW[4] = {160, 80, 40, 20};
  const int HH[4] = {92, 46, 23, 12};
  const int LS[4] = {0, 14720, 18400, 19320};

  float acc = 0.f;
  int cnt = 0;
  const int cbase = t & 0xE0;  // h*32

  for (int c = 0; c < NCAMS; ++c) {
    if (!mask[c * NQ + q]) continue;
    ++cnt;
    const __hip_bfloat16* vc = v + (size_t)c * (L_TOT * 256) + t;
#pragma unroll 8
    for (int s = 0; s < 32; ++s) {
      const int lvl = s >> 3;
      const int combo = cbase | s;
      const float x = sx[combo], y = sy[combo], w = sw[combo];
      const float fx0 = floorf(x), fy0 = floorf(y);
      const float fx = x - fx0, fy = y - fy0;
      const int x0 = (int)fx0, y0 = (int)fy0;
      const int Wi = WW[lvl], Hi = HH[lvl];
      const __hip_bfloat16* vl = vc + (size_t)LS[lvl] * 256;
      const bool xv0 = (x0 >= 0) & (x0 < Wi);
      const bool xv1 = (x0 + 1 >= 0) & (x0 + 1 < Wi);
      const float w00 = (1.f - fx) * (1.f - fy) * w;
      const float w01 = fx * (1.f - fy) * w;
      const float w10 = (1.f - fx) * fy * w;
      const float w11 = fx * fy * w;
      if (y0 >= 0 && y0 < Hi) {
        const __hip_bfloat16* row = vl + (size_t)(y0 * Wi) * 256;
        if (xv0) acc += w00 * __bfloat162float(row[x0 * 256]);
        if (xv1) acc += w01 * __bfloat162float(row[(x0 + 1) * 256]);
      }
      if (y0 + 1 >= 0 && y0 + 1 < Hi) {
        const __hip_bfloat16* row = vl + (size_t)((y0 + 1) * Wi) * 256;
        if (xv0) acc += w10 * __bfloat162float(row[x0 * 256]);
        if (xv1) acc += w11 * __bfloat162float(row[(x0 + 1) * 256]);
      }
    }
  }
  slots[(size_t)q * 256 + t] = acc / (float)max(cnt, 1);
}

// ---------------------------------------------------------------------------
extern "C" void kernel_launch(void* const* d_in, const int* in_sizes, int n_in,
                              void* d_out, int out_size, void* d_ws,
                              size_t ws_size, hipStream_t stream) {
  const float* query  = (const float*)d_in[0];
  // d_in[1] = key : UNUSED by the reference forward
  const float* value  = (const float*)d_in[2];
  const float* qpos   = (const float*)d_in[3];
  const float* refpts = (const float*)d_in[4];
  const void*  bmask  = d_in[5];
  // d_in[6] spatial_shapes, d_in[7] level_start_index: static, hardcoded
  const float* W_value = (const float*)d_in[8];
  const float* b_value = (const float*)d_in[9];
  const float* W_off   = (const float*)d_in[10];
  const float* b_off   = (const float*)d_in[11];
  const float* W_attn  = (const float*)d_in[12];
  const float* b_attn  = (const float*)d_in[13];
  const float* W_out   = (const float*)d_in[14];
  const float* b_out   = (const float*)d_in[15];
  float* out = (float*)d_out;

  // workspace layout
  unsigned short* ws_v = (unsigned short*)d_ws;              // 6*19560*256 bf16
  float* ws_off  = (float*)(ws_v + (size_t)NCAMS * L_TOT * 256); // 2500*512
  float* ws_log  = ws_off + (size_t)NQ * 512;                // 2500*256
  float* ws_q    = ws_log + (size_t)NQ * 256;                // 2500*256
  float* ws_slots = ws_q + (size_t)NQ * 256;                 // 2500*256
  unsigned char* ws_mask = (unsigned char*)(ws_slots + (size_t)NQ * 256);

  canon_mask_kernel<<<1, 256, 0, stream>>>(bmask, ws_mask);
  add_qpos_kernel<<<NQ, 256, 0, stream>>>(query, qpos, ws_q, NQ * 256);

  // off = q @ W_off^T + b_off          (2500 x 512)
  gemm_f32_kernel<false><<<dim3(40, 8), 256, 0, stream>>>(
      ws_q, W_off, b_off, nullptr, (void*)ws_off, NQ, 512);
  // logits = q @ W_attn^T + b_attn     (2500 x 256)
  gemm_f32_kernel<false><<<dim3(40, 4), 256, 0, stream>>>(
      ws_q, W_attn, b_attn, nullptr, (void*)ws_log, NQ, 256);
  // v = value @ W_value^T + b_value    (117360 x 256), bf16 out
  gemm_f32_kernel<true><<<dim3(1834, 4), 256, 0, stream>>>(
      value, W_value, b_value, nullptr, (void*)ws_v, NCAMS * L_TOT, 256);

  sampler_kernel<<<NQ, 256, 0, stream>>>(
      (const __hip_bfloat16*)ws_v, ws_off, ws_log, refpts, ws_mask, ws_slots);

  // out = slots @ W_out^T + b_out + query   (2500 x 256)
  gemm_f32_kernel<false><<<dim3(40, 4), 256, 0, stream>>>(
      ws_slots, W_out, b_out, query, (void*)out, NQ, 256);
}

// Round 2
// 471.968 us; speedup vs baseline: 1.5961x; 1.5961x over previous
//
#include <hip/hip_runtime.h>
#include <hip/hip_bf16.h>

// Static problem config (BEVFormer-base-ish, 50x50 BEV grid)
#define L_TOT   19560
#define NQ      2500
#define NCAMS   6
#define EMBED   256
#define M_VAL   (NCAMS * L_TOT)   // 117360

typedef __attribute__((ext_vector_type(8))) short short8;
typedef __attribute__((ext_vector_type(4))) float f32x4;

__device__ __forceinline__ unsigned short f2bf(float x) {
  __hip_bfloat16 h = __float2bfloat16(x);
  return *reinterpret_cast<unsigned short*>(&h);
}
__device__ __forceinline__ float bf_lo(unsigned int u) {
  return __uint_as_float(u << 16);
}
__device__ __forceinline__ float bf_hi(unsigned int u) {
  return __uint_as_float(u & 0xffff0000u);
}

// ---------------------------------------------------------------------------
// bev_mask dtype canonicalizer (bool may arrive as u8 / i32 / f32)
// ---------------------------------------------------------------------------
__global__ void canon_mask_kernel(const void* __restrict__ in,
                                  unsigned char* __restrict__ outm) {
  __shared__ int notI, notF;
  if (threadIdx.x == 0) { notI = 0; notF = 0; }
  __syncthreads();
  const unsigned int* w = (const unsigned int*)in;
  for (int i = threadIdx.x; i < 3750; i += 256) {
    unsigned int x = w[i];
    if (x != 0u && x != 1u)          atomicOr(&notI, 1);
    if (x != 0u && x != 0x3f800000u) atomicOr(&notF, 1);
  }
  __syncthreads();
  int mode = (notI == 0) ? 1 : ((notF == 0) ? 2 : 0); // 1=i32, 2=f32, 0=u8
  for (int i = threadIdx.x; i < NCAMS * NQ; i += 256) {
    unsigned char v;
    if (mode == 1)      v = (unsigned char)(w[i] != 0u);
    else if (mode == 2) v = (unsigned char)(((const float*)in)[i] != 0.0f);
    else                v = (unsigned char)(((const unsigned char*)in)[i] != 0);
    outm[i] = v;
  }
}

// ---------------------------------------------------------------------------
__global__ void add_qpos_kernel(const float* __restrict__ a,
                                const float* __restrict__ b,
                                float* __restrict__ o, int n) {
  int i = blockIdx.x * 256 + threadIdx.x;
  if (i < n) o[i] = a[i] + b[i];
}

__global__ void cvt_bf16_kernel(const float* __restrict__ in,
                                unsigned short* __restrict__ out, int n) {
  int i = blockIdx.x * 256 + threadIdx.x;
  if (i < n) out[i] = f2bf(in[i]);
}

// ---------------------------------------------------------------------------
// f32 GEMM (kept for the small q-side matmuls):
// C[M,N] = A[M,256] * B[N,256]^T + bias[N] (+ R[M,N])
// ---------------------------------------------------------------------------
template <bool BF16_OUT>
__global__ __launch_bounds__(256) void gemm_f32_kernel(
    const float* __restrict__ A, const float* __restrict__ B,
    const float* __restrict__ bias, const float* __restrict__ R,
    void* __restrict__ Cv, int M, int N) {
  __shared__ float As[16][68];
  __shared__ float Bs[16][68];
  const int tid = threadIdx.x;
  const int m0 = blockIdx.x * 64, n0 = blockIdx.y * 64;
  const int lr = tid >> 2;
  const int lk = (tid & 3) * 4;
  const int tm = tid >> 4;
  const int tn = tid & 15;

  const bool arow_ok = (m0 + lr) < M;
  const float* Ap = A + (size_t)(m0 + lr) * 256 + lk;
  const float* Bp = B + (size_t)(n0 + lr) * 256 + lk;

  float acc[4][4] = {};

  for (int kt = 0; kt < 16; ++kt) {
    float4 av = arow_ok ? *(const float4*)(Ap + kt * 16)
                        : make_float4(0.f, 0.f, 0.f, 0.f);
    float4 bv = *(const float4*)(Bp + kt * 16);
    __syncthreads();
    As[lk + 0][lr] = av.x; As[lk + 1][lr] = av.y;
    As[lk + 2][lr] = av.z; As[lk + 3][lr] = av.w;
    Bs[lk + 0][lr] = bv.x; Bs[lk + 1][lr] = bv.y;
    Bs[lk + 2][lr] = bv.z; Bs[lk + 3][lr] = bv.w;
    __syncthreads();
#pragma unroll
    for (int k = 0; k < 16; ++k) {
      const float4 a4 = *(const float4*)&As[k][tm * 4];
      const float4 b4 = *(const float4*)&Bs[k][tn * 4];
      const float aa[4] = {a4.x, a4.y, a4.z, a4.w};
      const float bb[4] = {b4.x, b4.y, b4.z, b4.w};
#pragma unroll
      for (int i = 0; i < 4; ++i)
#pragma unroll
        for (int j = 0; j < 4; ++j) acc[i][j] += aa[i] * bb[j];
    }
  }

  const int nb = n0 + tn * 4;
  float bsv[4] = {bias[nb], bias[nb + 1], bias[nb + 2], bias[nb + 3]};
#pragma unroll
  for (int i = 0; i < 4; ++i) {
    int m = m0 + tm * 4 + i;
    if (m >= M) continue;
    float o0 = acc[i][0] + bsv[0];
    float o1 = acc[i][1] + bsv[1];
    float o2 = acc[i][2] + bsv[2];
    float o3 = acc[i][3] + bsv[3];
    if (R != nullptr) {
      const float4 r4 = *(const float4*)&R[(size_t)m * N + nb];
      o0 += r4.x; o1 += r4.y; o2 += r4.z; o3 += r4.w;
    }
    if (BF16_OUT) {
      ushort4 u;
      u.x = f2bf(o0); u.y = f2bf(o1); u.z = f2bf(o2); u.w = f2bf(o3);
      *(ushort4*)((unsigned short*)Cv + (size_t)m * N + nb) = u;
    } else {
      float4 o; o.x = o0; o.y = o1; o.z = o2; o.w = o3;
      *(float4*)((float*)Cv + (size_t)m * N + nb) = o;
    }
  }
}

// ---------------------------------------------------------------------------
// Value projection, bf16 MFMA: C[m,n] = sum_k A_f32[m,k] * W_bf16[n,k] + b[n]
// 128x128 tile, 4 waves, 4x4 fragments of mfma_f32_16x16x32_bf16.
// f32 -> bf16 conversion fused into LDS staging.
// ---------------------------------------------------------------------------
__global__ __launch_bounds__(256) void vproj_mfma_kernel(
    const float* __restrict__ A, const unsigned short* __restrict__ Wbf,
    const float* __restrict__ bias, unsigned short* __restrict__ C, int M) {
  __shared__ unsigned short As[128 * 32];
  __shared__ unsigned short Bs[128 * 32];
  const int tid = threadIdx.x;
  const int m0 = blockIdx.x * 128;
  const int n0 = blockIdx.y * 128;
  const int wave = tid >> 6;
  const int lane = tid & 63;
  const int wm = (wave >> 1) * 64;
  const int wn = (wave & 1) * 64;
  const int fr = lane & 15;   // m (or n) within 16x16 tile
  const int fg = lane >> 4;   // k-group (8 contiguous k each)

  // staging: thread -> (row 0..127, col-offset 0/16)
  const int sr = tid >> 1;
  const int sc = (tid & 1) * 16;
  const bool a_ok = (m0 + sr) < M;
  const float* Ap = A + (size_t)(m0 + sr) * 256 + sc;
  const unsigned short* Bp = Wbf + (size_t)(n0 + sr) * 256 + sc;
  unsigned short* asr = &As[sr * 32 + sc];
  unsigned short* bsr = &Bs[sr * 32 + sc];

  f32x4 acc[4][4] = {};

  for (int kt = 0; kt < 8; ++kt) {
    float4 a4[4];
#pragma unroll
    for (int j = 0; j < 4; ++j)
      a4[j] = a_ok ? *(const float4*)(Ap + kt * 32 + 4 * j)
                   : make_float4(0.f, 0.f, 0.f, 0.f);
    uint4 b0 = *(const uint4*)(Bp + kt * 32);
    uint4 b1 = *(const uint4*)(Bp + kt * 32 + 8);
    __syncthreads();
#pragma unroll
    for (int j = 0; j < 4; ++j) {
      ushort4 u;
      u.x = f2bf(a4[j].x); u.y = f2bf(a4[j].y);
      u.z = f2bf(a4[j].z); u.w = f2bf(a4[j].w);
      *(ushort4*)(asr + 4 * j) = u;
    }
    *(uint4*)bsr = b0;
    *(uint4*)(bsr + 8) = b1;
    __syncthreads();

    short8 af[4], bfr[4];
#pragma unroll
    for (int mt = 0; mt < 4; ++mt)
      af[mt] = *(const short8*)&As[(wm + mt * 16 + fr) * 32 + fg * 8];
#pragma unroll
    for (int nt = 0; nt < 4; ++nt)
      bfr[nt] = *(const short8*)&Bs[(wn + nt * 16 + fr) * 32 + fg * 8];
#pragma unroll
    for (int mt = 0; mt < 4; ++mt)
#pragma unroll
      for (int nt = 0; nt < 4; ++nt)
        acc[mt][nt] = __builtin_amdgcn_mfma_f32_16x16x32_bf16(
            af[mt], bfr[nt], acc[mt][nt], 0, 0, 0);
  }

  // Epilogue: C/D layout col = lane&15, row = (lane>>4)*4 + reg
#pragma unroll
  for (int nt = 0; nt < 4; ++nt) {
    const int n = n0 + wn + nt * 16 + fr;
    const float bv = bias[n];
#pragma unroll
    for (int mt = 0; mt < 4; ++mt) {
      const int mbase = m0 + wm + mt * 16 + fg * 4;
#pragma unroll
      for (int r = 0; r < 4; ++r) {
        const int m = mbase + r;
        if (m < M) C[(size_t)m * 256 + n] = f2bf(acc[mt][nt][r] + bv);
      }
    }
  }
}

// ---------------------------------------------------------------------------
// Sampler v2: one block per (cam, query) pair; 128 threads, 2 channels each.
// Branchless clamped bilinear taps; atomicAdd into zeroed slots.
// ---------------------------------------------------------------------------
__global__ __launch_bounds__(128) void sampler2_kernel(
    const unsigned short* __restrict__ v, const float* __restrict__ off,
    const float* __restrict__ logits, const float* __restrict__ ref,
    const unsigned char* __restrict__ mask, float* __restrict__ slots) {
  const int pair = blockIdx.x;                 // c * NQ + q
  if (!mask[pair]) return;
  const int c = pair / NQ;
  const int q = pair - c * NQ;
  const int tt = threadIdx.x;                  // 0..127

  __shared__ float sx[256], sy[256], sw[256];
  {
    const float Wl[4] = {160.f, 80.f, 40.f, 20.f};
    const float Hl[4] = {92.f, 46.f, 23.f, 12.f};
#pragma unroll
    for (int rep = 0; rep < 2; ++rep) {
      const int combo = tt + rep * 128;        // (h,l,p): h=combo>>5
      const int l = (combo >> 3) & 3;
      const int p = combo & 7;
      const int z = p & 3;                     // NP//NZ x NZ reshape
      const float2 rz = ((const float2*)ref)[q * 4 + z];
      const float2 o2 = ((const float2*)off)[(size_t)q * 256 + combo];
      sx[combo] = rz.x * Wl[l] + o2.x - 0.5f;
      sy[combo] = rz.y * Hl[l] + o2.y - 0.5f;
      float lg = logits[q * 256 + combo];
      float mx = lg;
      for (int s = 16; s; s >>= 1) mx = fmaxf(mx, __shfl_xor(mx, s, 32));
      float e = __expf(lg - mx);
      float sm = e;
      for (int s = 16; s; s >>= 1) sm += __shfl_xor(sm, s, 32);
      sw[combo] = e / sm;
    }
  }
  __syncthreads();

  const int WW[4] = {160, 80, 40, 20};
  const int HH[4] = {92, 46, 23, 12};
  const int LS[4] = {0, 14720, 18400, 19320};

  // channel pair c0 = 2*tt; head h = tt>>4; dword gathers
  const unsigned int* vc =
      (const unsigned int*)(v + (size_t)c * (L_TOT * 256)) + tt;
  const int cbase = (tt >> 4) * 32;
  float acc0 = 0.f, acc1 = 0.f;

#pragma unroll 8
  for (int s = 0; s < 32; ++s) {
    const int lvl = s >> 3;
    const int combo = cbase + s;
    const float x = sx[combo], y = sy[combo], w = sw[combo];
    const float fx0 = floorf(x), fy0 = floorf(y);
    const float fx = x - fx0, fy = y - fy0;
    const int x0 = (int)fx0, y0 = (int)fy0;
    const int Wi = WW[lvl], Hi = HH[lvl];
    const int x0c = min(max(x0, 0), Wi - 1);
    const int x1c = min(max(x0 + 1, 0), Wi - 1);
    const int y0c = min(max(y0, 0), Hi - 1);
    const int y1c = min(max(y0 + 1, 0), Hi - 1);
    const float vx0 = (x0 >= 0 && x0 < Wi) ? 1.f : 0.f;
    const float vx1 = (x0 + 1 < Wi) ? 1.f : 0.f;   // x0+1 >= 0 iff x0 >= -1; guard both
    const float vx1b = (x0 + 1 >= 0) ? vx1 : 0.f;
    const float vy0 = (y0 >= 0 && y0 < Hi) ? 1.f : 0.f;
    const float vy1 = (y0 + 1 >= 0 && y0 + 1 < Hi) ? 1.f : 0.f;
    const unsigned int* vl = vc + (size_t)LS[lvl] * 128;
    const unsigned int u00 = vl[(y0c * Wi + x0c) * 128];
    const unsigned int u01 = vl[(y0c * Wi + x1c) * 128];
    const unsigned int u10 = vl[(y1c * Wi + x0c) * 128];
    const unsigned int u11 = vl[(y1c * Wi + x1c) * 128];
    const float w00 = (1.f - fx) * (1.f - fy) * vx0 * vy0 * w;
    const float w01 = fx * (1.f - fy) * vx1b * vy0 * w;
    const float w10 = (1.f - fx) * fy * vx0 * vy1 * w;
    const float w11 = fx * fy * vx1b * vy1 * w;
    acc0 += w00 * bf_lo(u00) + w01 * bf_lo(u01) +
            w10 * bf_lo(u10) + w11 * bf_lo(u11);
    acc1 += w00 * bf_hi(u00) + w01 * bf_hi(u01) +
            w10 * bf_hi(u10) + w11 * bf_hi(u11);
  }
  atomicAdd(&slots[q * 256 + tt * 2], acc0);
  atomicAdd(&slots[q * 256 + tt * 2 + 1], acc1);
}

// ---------------------------------------------------------------------------
__global__ void normalize_kernel(float* __restrict__ slots,
                                 const unsigned char* __restrict__ mask) {
  const int q = blockIdx.x;
  int cnt = 0;
#pragma unroll
  for (int c = 0; c < NCAMS; ++c) cnt += mask[c * NQ + q];
  const float inv = 1.f / (float)max(cnt, 1);
  slots[q * 256 + threadIdx.x] *= inv;
}

// ---------------------------------------------------------------------------
extern "C" void kernel_launch(void* const* d_in, const int* in_sizes, int n_in,
                              void* d_out, int out_size, void* d_ws,
                              size_t ws_size, hipStream_t stream) {
  const float* query  = (const float*)d_in[0];
  // d_in[1] = key : unused by the reference forward
  const float* value  = (const float*)d_in[2];
  const float* qpos   = (const float*)d_in[3];
  const float* refpts = (const float*)d_in[4];
  const void*  bmask  = d_in[5];
  const float* W_value = (const float*)d_in[8];
  const float* b_value = (const float*)d_in[9];
  const float* W_off   = (const float*)d_in[10];
  const float* b_off   = (const float*)d_in[11];
  const float* W_attn  = (const float*)d_in[12];
  const float* b_attn  = (const float*)d_in[13];
  const float* W_out   = (const float*)d_in[14];
  const float* b_out   = (const float*)d_in[15];
  float* out = (float*)d_out;

  // workspace layout (~73 MB)
  unsigned short* ws_v = (unsigned short*)d_ws;                  // M_VAL*256 bf16
  float* ws_off  = (float*)(ws_v + (size_t)M_VAL * 256);         // NQ*512
  float* ws_log  = ws_off + (size_t)NQ * 512;                    // NQ*256
  float* ws_q    = ws_log + (size_t)NQ * 256;                    // NQ*256
  float* ws_slots = ws_q + (size_t)NQ * 256;                     // NQ*256
  unsigned short* ws_wv = (unsigned short*)(ws_slots + (size_t)NQ * 256); // 256*256
  unsigned char* ws_mask = (unsigned char*)(ws_wv + 256 * 256);

  canon_mask_kernel<<<1, 256, 0, stream>>>(bmask, ws_mask);
  add_qpos_kernel<<<NQ, 256, 0, stream>>>(query, qpos, ws_q, NQ * 256);
  cvt_bf16_kernel<<<256, 256, 0, stream>>>(W_value, ws_wv, 256 * 256);

  // off = q @ W_off^T + b_off          (2500 x 512)
  gemm_f32_kernel<false><<<dim3(40, 8), 256, 0, stream>>>(
      ws_q, W_off, b_off, nullptr, (void*)ws_off, NQ, 512);
  // logits = q @ W_attn^T + b_attn     (2500 x 256)
  gemm_f32_kernel<false><<<dim3(40, 4), 256, 0, stream>>>(
      ws_q, W_attn, b_attn, nullptr, (void*)ws_log, NQ, 256);

  // v = value @ W_value^T + b_value    (117360 x 256), MFMA bf16
  vproj_mfma_kernel<<<dim3(917, 2), 256, 0, stream>>>(
      value, ws_wv, b_value, ws_v, M_VAL);

  hipMemsetAsync(ws_slots, 0, (size_t)NQ * 256 * sizeof(float), stream);
  sampler2_kernel<<<NCAMS * NQ, 128, 0, stream>>>(
      ws_v, ws_off, ws_log, refpts, ws_mask, ws_slots);
  normalize_kernel<<<NQ, 256, 0, stream>>>(ws_slots, ws_mask);

  // out = slots @ W_out^T + b_out + query   (2500 x 256)
  gemm_f32_kernel<false><<<dim3(40, 4), 256, 0, stream>>>(
      ws_slots, W_out, b_out, query, (void*)out, NQ, 256);
}

// Round 3
// 437.226 us; speedup vs baseline: 1.7230x; 1.0795x over previous
//
#include <hip/hip_runtime.h>
#include <hip/hip_bf16.h>

// Static problem config (BEVFormer-base-ish, 50x50 BEV grid)
#define L_TOT   19560
#define NQ      2500
#define NCAMS   6
#define M_VAL   (NCAMS * L_TOT)   // 117360

typedef __attribute__((ext_vector_type(8))) short short8;
typedef __attribute__((ext_vector_type(4))) float f32x4;

__device__ __forceinline__ unsigned short f2bf(float x) {
  __hip_bfloat16 h = __float2bfloat16(x);
  return *reinterpret_cast<unsigned short*>(&h);
}
__device__ __forceinline__ unsigned int pack2bf(float lo, float hi) {
  return (unsigned int)f2bf(lo) | ((unsigned int)f2bf(hi) << 16);
}
__device__ __forceinline__ float bf_lo(unsigned int u) {
  return __uint_as_float(u << 16);
}
__device__ __forceinline__ float bf_hi(unsigned int u) {
  return __uint_as_float(u & 0xffff0000u);
}

// ---------------------------------------------------------------------------
// bev_mask canonicalizer (bool may arrive as u8 / i32 / f32) + per-query 1/cnt
// ---------------------------------------------------------------------------
__global__ void canon_mask_kernel(const void* __restrict__ in,
                                  unsigned char* __restrict__ outm,
                                  float* __restrict__ invcnt) {
  __shared__ int notI, notF;
  if (threadIdx.x == 0) { notI = 0; notF = 0; }
  __syncthreads();
  const unsigned int* w = (const unsigned int*)in;
  for (int i = threadIdx.x; i < 3750; i += 256) {
    unsigned int x = w[i];
    if (x != 0u && x != 1u)          atomicOr(&notI, 1);
    if (x != 0u && x != 0x3f800000u) atomicOr(&notF, 1);
  }
  __syncthreads();
  int mode = (notI == 0) ? 1 : ((notF == 0) ? 2 : 0); // 1=i32, 2=f32, 0=u8
  for (int i = threadIdx.x; i < NCAMS * NQ; i += 256) {
    unsigned char v;
    if (mode == 1)      v = (unsigned char)(w[i] != 0u);
    else if (mode == 2) v = (unsigned char)(((const float*)in)[i] != 0.0f);
    else                v = (unsigned char)(((const unsigned char*)in)[i] != 0);
    outm[i] = v;
  }
  __syncthreads();
  for (int q = threadIdx.x; q < NQ; q += 256) {
    int cnt = 0;
#pragma unroll
    for (int c = 0; c < NCAMS; ++c) cnt += outm[c * NQ + q];
    invcnt[q] = 1.f / (float)max(cnt, 1);
  }
}

// ---------------------------------------------------------------------------
// Convert the 4 weight matrices to bf16 in one launch.
// segments: W_value 65536 | W_off 131072 | W_attn 65536 | W_out 65536
// ---------------------------------------------------------------------------
__global__ void cvt_weights_kernel(const float* __restrict__ w0,
                                   const float* __restrict__ w1,
                                   const float* __restrict__ w2,
                                   const float* __restrict__ w3,
                                   unsigned short* __restrict__ o0,
                                   unsigned short* __restrict__ o1,
                                   unsigned short* __restrict__ o2,
                                   unsigned short* __restrict__ o3) {
  int i = blockIdx.x * 256 + threadIdx.x;
  if (i < 65536)        o0[i] = f2bf(w0[i]);
  else if (i < 196608)  o1[i - 65536] = f2bf(w1[i - 65536]);
  else if (i < 262144)  o2[i - 196608] = f2bf(w2[i - 196608]);
  else if (i < 327680)  o3[i - 262144] = f2bf(w3[i - 262144]);
}

// ---------------------------------------------------------------------------
// Unified bf16-MFMA GEMM:  C[m, n] = sum_k (scale[m]*(A[m,k]+A2[m,k])) * W[n,k]
//                                   + bias[n] (+ R[m,n])
// A: f32 [M x 256] (converted to bf16 during LDS staging)
// W: bf16 [N x 256] prepacked.
// Operand swap: W = MFMA A-operand (m-index = channel), value rows = B-operand
// (n-index = row). D layout then gives each lane 4 CONSECUTIVE channels at a
// fixed row -> 8B/16B coalescable stores.
// LDS rows padded to 40 shorts (80 B): conflict-free b128 reads/writes.
// ---------------------------------------------------------------------------
template <bool BF16_OUT, bool HAS_A2, bool HAS_RES, bool HAS_SCALE>
__global__ __launch_bounds__(256) void gemm_mfma_kernel(
    const float* __restrict__ A, const float* __restrict__ A2,
    const unsigned short* __restrict__ Wbf, const float* __restrict__ bias,
    const float* __restrict__ R, const float* __restrict__ rowscale,
    void* __restrict__ Cv, int M, int N) {
  __shared__ unsigned short As[128 * 40];  // value/query rows
  __shared__ unsigned short Bs[128 * 40];  // weight rows (channels)
  const int tid = threadIdx.x;
  const int m0 = blockIdx.x * 128;
  const int n0 = blockIdx.y * 128;
  const int wave = tid >> 6;
  const int lane = tid & 63;
  const int wr = (wave >> 1) * 64;  // row-block within tile
  const int wc = (wave & 1) * 64;   // channel-block within tile
  const int fr = lane & 15;
  const int fg = lane >> 4;

  // staging: thread -> (row 0..127, 16-short half)
  const int sr = tid >> 1;
  const int sc = (tid & 1) * 16;
  const bool a_ok = (m0 + sr) < M;
  const float* Ap = A + (size_t)(m0 + sr) * 256 + sc;
  const float* A2p = HAS_A2 ? (A2 + (size_t)(m0 + sr) * 256 + sc) : nullptr;
  const float ascale = (HAS_SCALE && a_ok) ? rowscale[m0 + sr] : 1.f;
  const unsigned short* Bp = Wbf + (size_t)(n0 + sr) * 256 + sc;
  unsigned short* asw = &As[sr * 40 + sc];
  unsigned short* bsw = &Bs[sr * 40 + sc];

  f32x4 acc[4][4] = {};  // [ct(channel)][rt(row)]

  for (int kt = 0; kt < 8; ++kt) {
    float4 a4[4];
#pragma unroll
    for (int j = 0; j < 4; ++j) {
      a4[j] = a_ok ? *(const float4*)(Ap + kt * 32 + 4 * j)
                   : make_float4(0.f, 0.f, 0.f, 0.f);
      if (HAS_A2 && a_ok) {
        const float4 b4 = *(const float4*)(A2p + kt * 32 + 4 * j);
        a4[j].x += b4.x; a4[j].y += b4.y; a4[j].z += b4.z; a4[j].w += b4.w;
      }
      if (HAS_SCALE) {
        a4[j].x *= ascale; a4[j].y *= ascale;
        a4[j].z *= ascale; a4[j].w *= ascale;
      }
    }
    const uint4 b0 = *(const uint4*)(Bp + kt * 32);
    const uint4 b1 = *(const uint4*)(Bp + kt * 32 + 8);
    __syncthreads();
    uint4 u0, u1;
    u0.x = pack2bf(a4[0].x, a4[0].y); u0.y = pack2bf(a4[0].z, a4[0].w);
    u0.z = pack2bf(a4[1].x, a4[1].y); u0.w = pack2bf(a4[1].z, a4[1].w);
    u1.x = pack2bf(a4[2].x, a4[2].y); u1.y = pack2bf(a4[2].z, a4[2].w);
    u1.z = pack2bf(a4[3].x, a4[3].y); u1.w = pack2bf(a4[3].z, a4[3].w);
    *(uint4*)asw = u0;
    *(uint4*)(asw + 8) = u1;
    *(uint4*)bsw = b0;
    *(uint4*)(bsw + 8) = b1;
    __syncthreads();

    short8 wf[4], vf[4];
#pragma unroll
    for (int ct = 0; ct < 4; ++ct)
      wf[ct] = *(const short8*)&Bs[(wc + ct * 16 + fr) * 40 + fg * 8];
#pragma unroll
    for (int rt = 0; rt < 4; ++rt)
      vf[rt] = *(const short8*)&As[(wr + rt * 16 + fr) * 40 + fg * 8];
#pragma unroll
    for (int ct = 0; ct < 4; ++ct)
#pragma unroll
      for (int rt = 0; rt < 4; ++rt)
        acc[ct][rt] = __builtin_amdgcn_mfma_f32_16x16x32_bf16(
            wf[ct], vf[rt], acc[ct][rt], 0, 0, 0);
  }

  // Epilogue: D layout -> n(row of C) = fr, m(channel) = fg*4 + reg
#pragma unroll
  for (int rt = 0; rt < 4; ++rt) {
    const int m = m0 + wr + rt * 16 + fr;
    if (m >= M) continue;
#pragma unroll
    for (int ct = 0; ct < 4; ++ct) {
      const int ch = n0 + wc + ct * 16 + fg * 4;
      float o[4];
#pragma unroll
      for (int r = 0; r < 4; ++r) o[r] = acc[ct][rt][r] + bias[ch + r];
      if (HAS_RES) {
        const float4 r4 = *(const float4*)&R[(size_t)m * N + ch];
        o[0] += r4.x; o[1] += r4.y; o[2] += r4.z; o[3] += r4.w;
      }
      if (BF16_OUT) {
        ushort4 u;
        u.x = f2bf(o[0]); u.y = f2bf(o[1]); u.z = f2bf(o[2]); u.w = f2bf(o[3]);
        *(ushort4*)((unsigned short*)Cv + (size_t)m * N + ch) = u;
      } else {
        float4 of; of.x = o[0]; of.y = o[1]; of.z = o[2]; of.w = o[3];
        *(float4*)((float*)Cv + (size_t)m * N + ch) = of;
      }
    }
  }
}

// ---------------------------------------------------------------------------
// Sampler: one block per (cam, query) pair; 128 threads, 2 channels each.
// Branchless clamped bilinear taps; atomicAdd into zeroed slots.
// ---------------------------------------------------------------------------
__global__ __launch_bounds__(128) void sampler2_kernel(
    const unsigned short* __restrict__ v, const float* __restrict__ off,
    const float* __restrict__ logits, const float* __restrict__ ref,
    const unsigned char* __restrict__ mask, float* __restrict__ slots) {
  const int pair = blockIdx.x;                 // c * NQ + q
  if (!mask[pair]) return;
  const int c = pair / NQ;
  const int q = pair - c * NQ;
  const int tt = threadIdx.x;                  // 0..127

  __shared__ float sx[256], sy[256], sw[256];
  {
    const float Wl[4] = {160.f, 80.f, 40.f, 20.f};
    const float Hl[4] = {92.f, 46.f, 23.f, 12.f};
#pragma unroll
    for (int rep = 0; rep < 2; ++rep) {
      const int combo = tt + rep * 128;        // (h,l,p): h=combo>>5
      const int l = (combo >> 3) & 3;
      const int p = combo & 7;
      const int z = p & 3;                     // NP//NZ x NZ reshape
      const float2 rz = ((const float2*)ref)[q * 4 + z];
      const float2 o2 = ((const float2*)off)[(size_t)q * 256 + combo];
      sx[combo] = rz.x * Wl[l] + o2.x - 0.5f;
      sy[combo] = rz.y * Hl[l] + o2.y - 0.5f;
      float lg = logits[q * 256 + combo];
      float mx = lg;
      for (int s = 16; s; s >>= 1) mx = fmaxf(mx, __shfl_xor(mx, s, 32));
      float e = __expf(lg - mx);
      float sm = e;
      for (int s = 16; s; s >>= 1) sm += __shfl_xor(sm, s, 32);
      sw[combo] = e / sm;
    }
  }
  __syncthreads();

  const int WW[4] = {160, 80, 40, 20};
  const int HH[4] = {92, 46, 23, 12};
  const int LS[4] = {0, 14720, 18400, 19320};

  const unsigned int* vc =
      (const unsigned int*)(v + (size_t)c * (L_TOT * 256)) + tt;
  const int cbase = (tt >> 4) * 32;
  float acc0 = 0.f, acc1 = 0.f;

#pragma unroll 8
  for (int s = 0; s < 32; ++s) {
    const int lvl = s >> 3;
    const int combo = cbase + s;
    const float x = sx[combo], y = sy[combo], w = sw[combo];
    const float fx0 = floorf(x), fy0 = floorf(y);
    const float fx = x - fx0, fy = y - fy0;
    const int x0 = (int)fx0, y0 = (int)fy0;
    const int Wi = WW[lvl], Hi = HH[lvl];
    const int x0c = min(max(x0, 0), Wi - 1);
    const int x1c = min(max(x0 + 1, 0), Wi - 1);
    const int y0c = min(max(y0, 0), Hi - 1);
    const int y1c = min(max(y0 + 1, 0), Hi - 1);
    const float vx0 = (x0 >= 0 && x0 < Wi) ? 1.f : 0.f;
    const float vx1 = (x0 + 1 >= 0 && x0 + 1 < Wi) ? 1.f : 0.f;
    const float vy0 = (y0 >= 0 && y0 < Hi) ? 1.f : 0.f;
    const float vy1 = (y0 + 1 >= 0 && y0 + 1 < Hi) ? 1.f : 0.f;
    const unsigned int* vl = vc + (size_t)LS[lvl] * 128;
    const unsigned int u00 = vl[(y0c * Wi + x0c) * 128];
    const unsigned int u01 = vl[(y0c * Wi + x1c) * 128];
    const unsigned int u10 = vl[(y1c * Wi + x0c) * 128];
    const unsigned int u11 = vl[(y1c * Wi + x1c) * 128];
    const float w00 = (1.f - fx) * (1.f - fy) * vx0 * vy0 * w;
    const float w01 = fx * (1.f - fy) * vx1 * vy0 * w;
    const float w10 = (1.f - fx) * fy * vx0 * vy1 * w;
    const float w11 = fx * fy * vx1 * vy1 * w;
    acc0 += w00 * bf_lo(u00) + w01 * bf_lo(u01) +
            w10 * bf_lo(u10) + w11 * bf_lo(u11);
    acc1 += w00 * bf_hi(u00) + w01 * bf_hi(u01) +
            w10 * bf_hi(u10) + w11 * bf_hi(u11);
  }
  atomicAdd(&slots[q * 256 + tt * 2], acc0);
  atomicAdd(&slots[q * 256 + tt * 2 + 1], acc1);
}

// ---------------------------------------------------------------------------
extern "C" void kernel_launch(void* const* d_in, const int* in_sizes, int n_in,
                              void* d_out, int out_size, void* d_ws,
                              size_t ws_size, hipStream_t stream) {
  const float* query  = (const float*)d_in[0];
  // d_in[1] = key : unused by the reference forward
  const float* value  = (const float*)d_in[2];
  const float* qpos   = (const float*)d_in[3];
  const float* refpts = (const float*)d_in[4];
  const void*  bmask  = d_in[5];
  const float* W_value = (const float*)d_in[8];
  const float* b_value = (const float*)d_in[9];
  const float* W_off   = (const float*)d_in[10];
  const float* b_off   = (const float*)d_in[11];
  const float* W_attn  = (const float*)d_in[12];
  const float* b_attn  = (const float*)d_in[13];
  const float* W_out   = (const float*)d_in[14];
  const float* b_out   = (const float*)d_in[15];
  float* out = (float*)d_out;

  // workspace layout (~71 MB)
  unsigned short* ws_v = (unsigned short*)d_ws;                    // M_VAL*256 bf16
  unsigned short* ws_wv   = ws_v + (size_t)M_VAL * 256;            // 65536
  unsigned short* ws_woff = ws_wv + 65536;                         // 131072
  unsigned short* ws_wattn = ws_woff + 131072;                     // 65536
  unsigned short* ws_wout  = ws_wattn + 65536;                     // 65536
  float* ws_off   = (float*)(ws_wout + 65536);                     // NQ*512
  float* ws_log   = ws_off + (size_t)NQ * 512;                     // NQ*256
  float* ws_slots = ws_log + (size_t)NQ * 256;                     // NQ*256
  float* ws_invcnt = ws_slots + (size_t)NQ * 256;                  // NQ
  unsigned char* ws_mask = (unsigned char*)(ws_invcnt + NQ);       // NCAMS*NQ

  canon_mask_kernel<<<1, 256, 0, stream>>>(bmask, ws_mask, ws_invcnt);
  cvt_weights_kernel<<<1280, 256, 0, stream>>>(
      W_value, W_off, W_attn, W_out, ws_wv, ws_woff, ws_wattn, ws_wout);

  // off = (q+qpos) @ W_off^T + b_off          (2500 x 512)
  gemm_mfma_kernel<false, true, false, false><<<dim3(20, 4), 256, 0, stream>>>(
      query, qpos, ws_woff, b_off, nullptr, nullptr, (void*)ws_off, NQ, 512);
  // logits = (q+qpos) @ W_attn^T + b_attn     (2500 x 256)
  gemm_mfma_kernel<false, true, false, false><<<dim3(20, 2), 256, 0, stream>>>(
      query, qpos, ws_wattn, b_attn, nullptr, nullptr, (void*)ws_log, NQ, 256);
  // v = value @ W_value^T + b_value           (117360 x 256), bf16 out
  gemm_mfma_kernel<true, false, false, false><<<dim3(917, 2), 256, 0, stream>>>(
      value, nullptr, ws_wv, b_value, nullptr, nullptr, (void*)ws_v, M_VAL, 256);

  hipMemsetAsync(ws_slots, 0, (size_t)NQ * 256 * sizeof(float), stream);
  sampler2_kernel<<<NCAMS * NQ, 128, 0, stream>>>(
      ws_v, ws_off, ws_log, refpts, ws_mask, ws_slots);

  // out = (slots/cnt) @ W_out^T + b_out + query   (2500 x 256)
  gemm_mfma_kernel<false, false, true, true><<<dim3(20, 2), 256, 0, stream>>>(
      ws_slots, nullptr, ws_wout, b_out, query, ws_invcnt, (void*)out, NQ, 256);
}